// Round 6
// baseline (175.338 us; speedup 1.0000x reference)
//
#include <hip/hip_runtime.h>
#include <hip/hip_fp16.h>

// Volume: [B=2, X=128, Y=128, Z=128, C=1] fp32, grid: [B=2, N=2^21, 3] in [0,1].
// Output: [B, N, 1] fp32. image flat idx = b*2^21 + x*2^14 + y*2^7 + z.
//
// R1 naive fp32 gathers               180 us (FETCH 594 MB)
// R2 fp16 volume (L2-resident)        132 us (FETCH 127 MB)
// R3 z-pair 8B windows, 4 req/sample   91 us (FETCH 112 MB)
// R4 bin+LDS-tile pipeline    FAILED  148 us (scatter write-amp)
// R5 4 samples/thread, 16 loads in    91 us -> MLP-invariant: gather pipe is
//    flight                                    a THROUGHPUT wall, ~3.3cy/req
// R6 discriminator: L1-bypass (sc0) on gathers. Volume can't live in 32KiB
//    L1 anyway (4.19 MiB random): if the wall is TCP tag/allocate, sc0 drops
//    per-request cost toward the L2-channel bound (~55-70us). If neutral,
//    the wall is L2 request throughput -> structural ceiling.

#define TOTAL   (2 * 2097152)   // B * N samples
#define LOG2N   21              // N = 2^21 per batch; VOL = 2^21 voxels
#define VOL     (128 * 128 * 128)
#define NVOX    (2 * VOL)
#define SPB     4               // samples per thread

typedef unsigned long long u64;

// ---- pre-pass: fp32 volume -> fp16 volume in workspace -------------------
__global__ __launch_bounds__(256)
void ImageWarped_cvt_fp16_kernel(const float* __restrict__ in,
                                 __half* __restrict__ out)
{
    const int i = blockIdx.x * 256 + threadIdx.x;   // NVOX/4 threads
    const float4 v = ((const float4*)in)[i];
    union { __half2 h2[2]; uint2 u; } p;
    p.h2[0] = __floats2half2_rn(v.x, v.y);
    p.h2[1] = __floats2half2_rn(v.z, v.w);
    ((uint2*)out)[i] = p.u;
}

// L1-bypassing 8B gather: global_load_dwordx2 with sc0 (gfx950 flag; the
// old `glc` spelling does not assemble). Result arrives after s_waitcnt.
__device__ __forceinline__ u64 load8_sc0(const __half* p)
{
    u64 v;
    asm volatile("global_load_dwordx2 %0, %1, off sc0"
                 : "=v"(v)
                 : "v"((u64)(uintptr_t)p));
    return v;
}

// ---- main: 4 samples/thread, 16 sc0 gathers in flight --------------------
__global__ __launch_bounds__(256)
void ImageWarped_trilinear_h4s_kernel(const __half* __restrict__ image,
                                      const float* __restrict__ grid,
                                      float* __restrict__ out)
{
    // Batch-parity swizzle: round-robin blockIdx%8 -> XCD keeps one batch's
    // 4.19 MiB fp16 volume per XCD L2.
    const int batch = blockIdx.x & 1;
    const int t     = (blockIdx.x >> 1) * 256 + threadIdx.x;
    const int i0    = (batch << LOG2N) | (t << 2);   // 4 consecutive samples

    const float4* __restrict__ G4 = (const float4*)grid;
    const int fb = (3 * i0) >> 2;
    const float4 ga = G4[fb + 0];
    const float4 gb = G4[fb + 1];
    const float4 gc = G4[fb + 2];

    const float cx[SPB] = { ga.x, ga.w, gb.z, gc.y };
    const float cy[SPB] = { ga.y, gb.x, gb.w, gc.z };
    const float cz[SPB] = { ga.z, gb.y, gc.x, gc.w };

    const __half* __restrict__ img = image + ((size_t)batch << LOG2N);

    float wxa[SPB], wx2a[SPB], wya[SPB], wy2a[SPB], wza[SPB], wz2a[SPB];
    int   sha[SPB];
    u64   w11[SPB], w21[SPB], w12[SPB], w22[SPB];

    // Phase 1: addresses + ALL 16 gathers issued (sc0 = straight to L2).
    #pragma unroll
    for (int k = 0; k < SPB; ++k) {
        const float xf = fminf(fmaxf(cx[k] * 128.0f, 0.001f), 126.999f);
        const float yf = fminf(fmaxf(cy[k] * 128.0f, 0.001f), 126.999f);
        const float zf = fminf(fmaxf(cz[k] * 128.0f, 0.001f), 126.999f);

        const float x1f = floorf(xf), x2f = ceilf(xf);
        const float y1f = floorf(yf), y2f = ceilf(yf);
        const float z1f = floorf(zf), z2f = ceilf(zf);

        // Literal reference weights (integral coord -> both weights 0).
        wxa[k] = xf - x1f;  wx2a[k] = x2f - xf;
        wya[k] = yf - y1f;  wy2a[k] = y2f - yf;
        wza[k] = zf - z1f;  wz2a[k] = z2f - zf;

        const int bx1 = ((int)x1f) << 14, bx2 = ((int)x2f) << 14;
        const int by1 = ((int)y1f) << 7,  by2 = ((int)y2f) << 7;
        const int iz1 = (int)z1f;

        // 4-half window [ze, ze+3]: contains z1,z1+1; 4B-aligned; in-bounds.
        const int ze = min(iz1 & ~1, 124);
        sha[k] = (iz1 - ze) << 4;

        const __half* p = img + ze;
        w11[k] = load8_sc0(p + bx1 + by1);
        w21[k] = load8_sc0(p + bx2 + by1);
        w12[k] = load8_sc0(p + bx1 + by2);
        w22[k] = load8_sc0(p + bx2 + by2);
    }

    // Fence: inline-asm loads are invisible to the compiler's waitcnt pass.
    // Tie every loaded value through the barrier so no use is scheduled
    // before the wait.
    asm volatile("s_waitcnt vmcnt(0)"
                 : "+v"(w11[0]), "+v"(w21[0]), "+v"(w12[0]), "+v"(w22[0]),
                   "+v"(w11[1]), "+v"(w21[1]), "+v"(w12[1]), "+v"(w22[1]),
                   "+v"(w11[2]), "+v"(w21[2]), "+v"(w12[2]), "+v"(w22[2]),
                   "+v"(w11[3]), "+v"(w21[3]), "+v"(w12[3]), "+v"(w22[3])
                 :
                 : "memory");

    // Phase 2: extract z-pairs, lerp, pack float4 result.
    float res[SPB];
    #pragma unroll
    for (int k = 0; k < SPB; ++k) {
        auto zl = [&](u64 w) -> float {
            w >>= sha[k];
            union { unsigned int u32; __half2 h; } c;
            c.u32 = (unsigned int)w;            // (c_z1, c_z2)
            const float2 f = __half22float2(c.h);
            return f.x * wz2a[k] + f.y * wza[k];   // literal z-lerp
        };
        const float q11 = zl(w11[k]);
        const float q21 = zl(w21[k]);
        const float q12 = zl(w12[k]);
        const float q22 = zl(w22[k]);
        res[k] = (q21 * wxa[k] + q11 * wx2a[k]) * wy2a[k]
               + (q22 * wxa[k] + q12 * wx2a[k]) * wya[k];
    }

    float4 o; o.x = res[0]; o.y = res[1]; o.z = res[2]; o.w = res[3];
    ((float4*)out)[i0 >> 2] = o;
}

// ---- fallback: direct fp32 gathers (if ws too small) ---------------------
__global__ __launch_bounds__(256)
void ImageWarped_trilinear_f_kernel(const float* __restrict__ image,
                                    const float* __restrict__ grid,
                                    float* __restrict__ out)
{
    const int i = blockIdx.x * 256 + threadIdx.x;
    if (i >= TOTAL) return;
    const float gx = grid[3 * i + 0];
    const float gy = grid[3 * i + 1];
    const float gz = grid[3 * i + 2];
    const float* __restrict__ img = image + ((size_t)(i >> LOG2N) << LOG2N);

    const float xf = fminf(fmaxf(gx * 128.0f, 0.001f), 126.999f);
    const float yf = fminf(fmaxf(gy * 128.0f, 0.001f), 126.999f);
    const float zf = fminf(fmaxf(gz * 128.0f, 0.001f), 126.999f);

    const float x1f = floorf(xf), x2f = ceilf(xf);
    const float y1f = floorf(yf), y2f = ceilf(yf);
    const float z1f = floorf(zf), z2f = ceilf(zf);
    const float wx = xf - x1f, wx2 = x2f - xf;
    const float wy = yf - y1f, wy2 = y2f - yf;
    const float wz = zf - z1f, wz2 = z2f - zf;

    const int bx1 = ((int)x1f) << 14, bx2 = ((int)x2f) << 14;
    const int by1 = ((int)y1f) << 7,  by2 = ((int)y2f) << 7;
    const int iz1 = (int)z1f,         iz2 = (int)z2f;

    const float c111 = img[bx1 + by1 + iz1], c211 = img[bx2 + by1 + iz1];
    const float c121 = img[bx1 + by2 + iz1], c221 = img[bx2 + by2 + iz1];
    const float c112 = img[bx1 + by1 + iz2], c212 = img[bx2 + by1 + iz2];
    const float c122 = img[bx1 + by2 + iz2], c222 = img[bx2 + by2 + iz2];

    const float l1 = (c211 * wx + c111 * wx2) * wy2 + (c221 * wx + c121 * wx2) * wy;
    const float l2 = (c212 * wx + c112 * wx2) * wy2 + (c222 * wx + c122 * wx2) * wy;
    out[i] = l2 * wz + l1 * wz2;
}

extern "C" void kernel_launch(void* const* d_in, const int* in_sizes, int n_in,
                              void* d_out, int out_size, void* d_ws, size_t ws_size,
                              hipStream_t stream)
{
    const float* image = (const float*)d_in[0];  // [2,128,128,128,1] fp32
    const float* grid  = (const float*)d_in[1];  // [2,2097152,3]     fp32
    float* out = (float*)d_out;                  // [2,2097152,1]     fp32

    if (ws_size >= (size_t)NVOX * sizeof(__half)) {
        __half* img16 = (__half*)d_ws;
        ImageWarped_cvt_fp16_kernel<<<NVOX / 4 / 256, 256, 0, stream>>>(image, img16);
        ImageWarped_trilinear_h4s_kernel<<<TOTAL / (256 * SPB), 256, 0, stream>>>(
            img16, grid, out);
    } else {
        ImageWarped_trilinear_f_kernel<<<TOTAL / 256, 256, 0, stream>>>(image, grid, out);
    }
}